// Round 2
// baseline (114.999 us; speedup 1.0000x reference)
//
#include <hip/hip_runtime.h>

// BallQLoss: ball_query(pc, r=0.2, k=16) against itself + L1 grouping loss.
// pc: (4, 4096, 3) f32, mask: (4, 4096, 30) f32 -> scalar f32.
// One wave per query. Phase 1: ballot-scan with 2-deep prefetch collects the
// first <=16 in-ball indices (ascending, padded with first — reference
// semantics). Phase 2: slot-distributed gather (4 lanes/slot, strided
// channels) issues all L1-diff loads independently (single latency exposure).

#define BQ_B 4
#define BQ_N 4096
#define BQ_C 30
#define BQ_K 16
#define BQ_R2 0.04f
#define WAVES_PER_BLOCK 4
#define BLOCK_T (WAVES_PER_BLOCK * 64)

__global__ __launch_bounds__(BLOCK_T) void ballq_loss_kernel(
    const float* __restrict__ pc,    // (B, N, 3)
    const float* __restrict__ mask,  // (B, N, C)
    float* __restrict__ out)         // scalar
{
    const int tid  = threadIdx.x;
    const int lane = tid & 63;
    const int wave = tid >> 6;
    const int query = blockIdx.x * WAVES_PER_BLOCK + wave;  // [0, B*N)
    const int b = query >> 12;        // / N
    const int n = query & (BQ_N - 1); // % N

    const float* pcb   = pc   + (size_t)b * BQ_N * 3;
    const float* maskb = mask + (size_t)b * BQ_N * BQ_C;

    const float qx = pcb[n * 3 + 0];
    const float qy = pcb[n * 3 + 1];
    const float qz = pcb[n * 3 + 2];

    // ---- Phase 1: scan candidates in ascending order, 2-deep prefetch ----
    int found  = 0;
    int first  = 0;   // self is always in-ball, so found >= 1 always
    int my_sel = 0;   // lane s (<16) holds the neighbor index for slot s

    float cx = pcb[lane * 3 + 0];
    float cy = pcb[lane * 3 + 1];
    float cz = pcb[lane * 3 + 2];
    float nx = pcb[(64 + lane) * 3 + 0];
    float ny = pcb[(64 + lane) * 3 + 1];
    float nz = pcb[(64 + lane) * 3 + 2];

    for (int base = 0; base < BQ_N; base += 64) {
        const float dx = cx - qx, dy = cy - qy, dz = cz - qz;
        const float d2 = dx * dx + dy * dy + dz * dz;
        // Prefetch chunk base+128 (clamped; wasted-but-safe on early exit).
        const int pf = min(base + 128 + lane, BQ_N - 1);
        const float px = pcb[pf * 3 + 0];
        const float py = pcb[pf * 3 + 1];
        const float pz = pcb[pf * 3 + 2];

        unsigned long long bal = __ballot(d2 < BQ_R2);
        while (bal && found < BQ_K) {           // wave-uniform peel
            const int bit = __builtin_ctzll(bal);
            bal &= bal - 1;
            const int msel = base + bit;
            if (found == 0) first = msel;
            if (lane == found) my_sel = msel;
            ++found;
        }
        if (found >= BQ_K) break;
        cx = nx; cy = ny; cz = nz;
        nx = px; ny = py; nz = pz;
    }
    // Pad remaining slots with the first found index (reference semantics).
    if (lane < BQ_K && lane >= found) my_sel = first;

    // ---- Phase 2: gather. slot = lane>>2 (4 lanes/slot), channels (lane&3)+4j
    const int slot = lane >> 2;
    const int c0   = lane & 3;
    const int nb   = __shfl(my_sel, slot, 64);
    const float* nrow = maskb + (size_t)nb * BQ_C;
    const float* qrow = maskb + (size_t)n  * BQ_C;

    float lsum = 0.f;
    #pragma unroll
    for (int j = 0; j < 8; ++j) {
        const int c = c0 + 4 * j;
        if (c < BQ_C) lsum += fabsf(qrow[c] - nrow[c]);
    }

    // Wave reduction (64 lanes).
    for (int off = 32; off > 0; off >>= 1)
        lsum += __shfl_xor(lsum, off, 64);

    __shared__ float wsum[WAVES_PER_BLOCK];
    if (lane == 0) wsum[wave] = lsum;
    __syncthreads();
    if (tid == 0) {
        float s = 0.f;
        #pragma unroll
        for (int w = 0; w < WAVES_PER_BLOCK; ++w) s += wsum[w];
        atomicAdd(out, s * (1.0f / ((float)BQ_B * BQ_N * BQ_K)));
    }
}

extern "C" void kernel_launch(void* const* d_in, const int* in_sizes, int n_in,
                              void* d_out, int out_size, void* d_ws, size_t ws_size,
                              hipStream_t stream) {
    const float* pc   = (const float*)d_in[0];  // (4, 4096, 3)
    const float* mask = (const float*)d_in[1];  // (4, 4096, 30)
    float* out = (float*)d_out;

    // d_out is poisoned 0xAA before every timed launch — zero it (capture-safe).
    hipMemsetAsync(out, 0, sizeof(float), stream);

    const int n_query = BQ_B * BQ_N;
    const int grid = n_query / WAVES_PER_BLOCK;  // 4096 blocks
    ballq_loss_kernel<<<grid, BLOCK_T, 0, stream>>>(pc, mask, out);
}

// Round 3
// 92.609 us; speedup vs baseline: 1.2418x; 1.2418x over previous
//
#include <hip/hip_runtime.h>

// BallQLoss: ball_query(pc, r=0.2, k=16) against itself + L1 grouping loss.
// pc: (4, 4096, 3) f32, mask: (4, 4096, 30) f32 -> scalar f32.
// R3: pc staged in LDS (all waves in a block share one batch's 48 KB), scan
// from LDS with 1-deep register prefetch; interleaved dual-neighbor gather
// (lanes 0-29 = neighbor A channels, lanes 32-61 = neighbor B channels).

#define BQ_B 4
#define BQ_N 4096
#define BQ_C 30
#define BQ_K 16
#define BQ_R2 0.04f
#define WAVES_PER_BLOCK 8
#define BLOCK_T (WAVES_PER_BLOCK * 64)

__global__ __launch_bounds__(BLOCK_T) void ballq_loss_kernel(
    const float* __restrict__ pc,    // (B, N, 3)
    const float* __restrict__ mask,  // (B, N, C)
    float* __restrict__ out)         // scalar
{
    __shared__ float spc[BQ_N * 3];          // 48 KB: this batch's points
    __shared__ float wsum[WAVES_PER_BLOCK];

    const int tid  = threadIdx.x;
    const int lane = tid & 63;
    const int wave = tid >> 6;
    const int query = blockIdx.x * WAVES_PER_BLOCK + wave;  // [0, B*N)
    const int b = query >> 12;        // all waves in a block share one batch
    const int n = query & (BQ_N - 1);

    const float* pcb   = pc   + (size_t)b * BQ_N * 3;
    const float* maskb = mask + (size_t)b * BQ_N * BQ_C;

    // Cooperative stage: 12288 floats = 3072 float4 / 512 threads = 6 each.
    {
        const float4* src = (const float4*)pcb;
        float4* dst = (float4*)spc;
        #pragma unroll
        for (int i = 0; i < (BQ_N * 3 / 4) / BLOCK_T; ++i)
            dst[tid + i * BLOCK_T] = src[tid + i * BLOCK_T];
    }
    __syncthreads();

    const float qx = spc[n * 3 + 0];
    const float qy = spc[n * 3 + 1];
    const float qz = spc[n * 3 + 2];
    const int   ch = lane & 31;  // channel index for both gather halves
    const float qv = (ch < BQ_C) ? maskb[(size_t)n * BQ_C + ch] : 0.f;

    int   found = 0;
    int   first = 0;   // self always in-ball, so found >= 1
    float lsum  = 0.f;

    float cx = spc[lane * 3 + 0];
    float cy = spc[lane * 3 + 1];
    float cz = spc[lane * 3 + 2];

    for (int base = 0; base < BQ_N; base += 64) {
        // 1-deep LDS prefetch of the next chunk (cheap; wasted on exit only).
        const int nbase = (base + 64 < BQ_N) ? base + 64 : 0;
        const float nx = spc[(nbase + lane) * 3 + 0];
        const float ny = spc[(nbase + lane) * 3 + 1];
        const float nz = spc[(nbase + lane) * 3 + 2];

        const float dx = cx - qx, dy = cy - qy, dz = cz - qz;
        const float d2 = dx * dx + dy * dy + dz * dz;
        unsigned long long bal = __ballot(d2 < BQ_R2);

        // Peel up to two in-ball indices per iteration (ascending order).
        while (bal && found < BQ_K) {
            const int bit0 = __builtin_ctzll(bal); bal &= bal - 1;
            const int m0 = base + bit0;
            if (found == 0) first = m0;
            int m1 = -1;
            if (bal && found + 1 < BQ_K) {
                const int bit1 = __builtin_ctzll(bal); bal &= bal - 1;
                m1 = base + bit1;
            }
            const int mm = (lane < 32) ? m0 : m1;
            if (ch < BQ_C && mm >= 0)
                lsum += fabsf(qv - maskb[(size_t)mm * BQ_C + ch]);
            found += (m1 >= 0) ? 2 : 1;
        }
        if (found >= BQ_K) break;
        cx = nx; cy = ny; cz = nz;
    }
    // Pad remaining slots with first found index (reference semantics).
    // Only the lower half contributes (lane == channel here).
    if (found < BQ_K && lane < BQ_C)
        lsum += (float)(BQ_K - found) * fabsf(qv - maskb[(size_t)first * BQ_C + lane]);

    // Wave reduction (64 lanes).
    for (int off = 32; off > 0; off >>= 1)
        lsum += __shfl_xor(lsum, off, 64);

    if (lane == 0) wsum[wave] = lsum;
    __syncthreads();
    if (tid == 0) {
        float s = 0.f;
        #pragma unroll
        for (int w = 0; w < WAVES_PER_BLOCK; ++w) s += wsum[w];
        atomicAdd(out, s * (1.0f / ((float)BQ_B * BQ_N * BQ_K)));
    }
}

extern "C" void kernel_launch(void* const* d_in, const int* in_sizes, int n_in,
                              void* d_out, int out_size, void* d_ws, size_t ws_size,
                              hipStream_t stream) {
    const float* pc   = (const float*)d_in[0];  // (4, 4096, 3)
    const float* mask = (const float*)d_in[1];  // (4, 4096, 30)
    float* out = (float*)d_out;

    // d_out is poisoned 0xAA before every timed launch — zero it (capture-safe).
    hipMemsetAsync(out, 0, sizeof(float), stream);

    const int n_query = BQ_B * BQ_N;
    const int grid = n_query / WAVES_PER_BLOCK;  // 2048 blocks
    ballq_loss_kernel<<<grid, BLOCK_T, 0, stream>>>(pc, mask, out);
}

// Round 4
// 80.872 us; speedup vs baseline: 1.4220x; 1.1451x over previous
//
#include <hip/hip_runtime.h>

// BallQLoss: ball_query(pc, r=0.2, k=16) against itself + L1 grouping loss.
// pc: (4, 4096, 3) f32, mask: (4, 4096, 30) f32 -> scalar f32.
// R4: NO global atomics (R2's block-count regression fingered same-address
// atomicAdd serialization ~30cy each as a ~26us floor). Blocks write partial
// sums to d_ws; 1-block finisher kernel reduces. Grid 768 blocks (3/CU, one
// residency round); each wave grid-strides 2-3 queries per staged pc tile.

#define BQ_B 4
#define BQ_N 4096
#define BQ_C 30
#define BQ_K 16
#define BQ_R2 0.04f
#define WAVES_PER_BLOCK 8
#define BLOCK_T (WAVES_PER_BLOCK * 64)
#define BLOCKS_PER_BATCH 192
#define GRID (BQ_B * BLOCKS_PER_BATCH)                    // 768
#define WAVES_PER_BATCH (BLOCKS_PER_BATCH * WAVES_PER_BLOCK)  // 1536

__global__ __launch_bounds__(BLOCK_T) void ballq_scan_kernel(
    const float* __restrict__ pc,    // (B, N, 3)
    const float* __restrict__ mask,  // (B, N, C)
    float* __restrict__ partial)     // (GRID,) unscaled per-block sums
{
    __shared__ __align__(16) float spc[BQ_N * 3];  // 48 KB: this batch's pc
    __shared__ float wsum[WAVES_PER_BLOCK];

    const int tid  = threadIdx.x;
    const int lane = tid & 63;
    const int wave = tid >> 6;
    const int b        = blockIdx.x / BLOCKS_PER_BATCH;
    const int blk_in_b = blockIdx.x % BLOCKS_PER_BATCH;

    const float* pcb   = pc   + (size_t)b * BQ_N * 3;
    const float* maskb = mask + (size_t)b * BQ_N * BQ_C;

    // Cooperative stage: 12288 floats = 3072 float4 / 512 threads = 6 each.
    {
        const float4* src = (const float4*)pcb;
        float4* dst = (float4*)spc;
        #pragma unroll
        for (int i = 0; i < (BQ_N * 3 / 4) / BLOCK_T; ++i)
            dst[tid + i * BLOCK_T] = src[tid + i * BLOCK_T];
    }
    __syncthreads();

    const int ch = lane & 31;  // channel index for both gather halves
    float acc = 0.f;           // per-lane sum across this wave's queries

    // Each wave handles queries n = blk_in_b*8 + wave + it*1536 (2-3 each).
    for (int n = blk_in_b * WAVES_PER_BLOCK + wave; n < BQ_N; n += WAVES_PER_BATCH) {
        const float qx = spc[n * 3 + 0];
        const float qy = spc[n * 3 + 1];
        const float qz = spc[n * 3 + 2];
        const float qv = (ch < BQ_C) ? maskb[(size_t)n * BQ_C + ch] : 0.f;

        int   found = 0;
        int   first = 0;   // self always in-ball => found >= 1
        float lsum  = 0.f;

        float cx = spc[lane * 3 + 0];
        float cy = spc[lane * 3 + 1];
        float cz = spc[lane * 3 + 2];

        for (int base = 0; base < BQ_N; base += 64) {
            // 1-deep LDS prefetch of the next chunk.
            const int nbase = (base + 64 < BQ_N) ? base + 64 : 0;
            const float nx = spc[(nbase + lane) * 3 + 0];
            const float ny = spc[(nbase + lane) * 3 + 1];
            const float nz = spc[(nbase + lane) * 3 + 2];

            const float dx = cx - qx, dy = cy - qy, dz = cz - qz;
            const float d2 = dx * dx + dy * dy + dz * dz;
            unsigned long long bal = __ballot(d2 < BQ_R2);

            // Peel up to two in-ball indices per iteration (ascending order).
            while (bal && found < BQ_K) {
                const int bit0 = __builtin_ctzll(bal); bal &= bal - 1;
                const int m0 = base + bit0;
                if (found == 0) first = m0;
                int m1 = -1;
                if (bal && found + 1 < BQ_K) {
                    const int bit1 = __builtin_ctzll(bal); bal &= bal - 1;
                    m1 = base + bit1;
                }
                const int mm = (lane < 32) ? m0 : m1;
                if (ch < BQ_C && mm >= 0)
                    lsum += fabsf(qv - maskb[(size_t)mm * BQ_C + ch]);
                found += (m1 >= 0) ? 2 : 1;
            }
            if (found >= BQ_K) break;
            cx = nx; cy = ny; cz = nz;
        }
        // Pad remaining slots with first found index (reference semantics);
        // lower half only (lane == channel here).
        if (found < BQ_K && lane < BQ_C)
            lsum += (float)(BQ_K - found) * fabsf(qv - maskb[(size_t)first * BQ_C + lane]);

        acc += lsum;
    }

    // Wave reduction (64 lanes) of the accumulated per-lane sums.
    for (int off = 32; off > 0; off >>= 1)
        acc += __shfl_xor(acc, off, 64);

    if (lane == 0) wsum[wave] = acc;
    __syncthreads();
    if (tid == 0) {
        float s = 0.f;
        #pragma unroll
        for (int w = 0; w < WAVES_PER_BLOCK; ++w) s += wsum[w];
        partial[blockIdx.x] = s;   // non-atomic per-block partial
    }
}

__global__ __launch_bounds__(256) void ballq_finish_kernel(
    const float* __restrict__ partial, float* __restrict__ out)
{
    float s = 0.f;
    for (int i = threadIdx.x; i < GRID; i += 256) s += partial[i];
    for (int off = 32; off > 0; off >>= 1)
        s += __shfl_xor(s, off, 64);
    __shared__ float ws[4];
    if ((threadIdx.x & 63) == 0) ws[threadIdx.x >> 6] = s;
    __syncthreads();
    if (threadIdx.x == 0)
        out[0] = (ws[0] + ws[1] + ws[2] + ws[3]) *
                 (1.0f / ((float)BQ_B * BQ_N * BQ_K));
}

extern "C" void kernel_launch(void* const* d_in, const int* in_sizes, int n_in,
                              void* d_out, int out_size, void* d_ws, size_t ws_size,
                              hipStream_t stream) {
    const float* pc   = (const float*)d_in[0];  // (4, 4096, 3)
    const float* mask = (const float*)d_in[1];  // (4, 4096, 30)
    float* out     = (float*)d_out;
    float* partial = (float*)d_ws;              // GRID floats = 3 KB scratch

    ballq_scan_kernel<<<GRID, BLOCK_T, 0, stream>>>(pc, mask, partial);
    ballq_finish_kernel<<<1, 256, 0, stream>>>(partial, out);
}

// Round 5
// 77.811 us; speedup vs baseline: 1.4779x; 1.0393x over previous
//
#include <hip/hip_runtime.h>

// BallQLoss: ball_query(pc, r=0.2, k=16) against itself + L1 grouping loss.
// pc: (4, 4096, 3) f32, mask: (4, 4096, 30) f32 -> scalar f32.
// R5: phase-split. Scan loop peels indices ONLY (no memory in the peel;
// lane s captures slot s's index). Then a batched gather issues 16
// independent wave-coalesced row loads (v_readlane SGPR base, 30 lanes on
// one 120B row => 2 lines/instr) — one latency exposure instead of ~8
// serialized ones. Partial sums to d_ws; 1-block finisher (no atomics).

#define BQ_B 4
#define BQ_N 4096
#define BQ_C 30
#define BQ_K 16
#define BQ_R2 0.04f
#define WAVES_PER_BLOCK 8
#define BLOCK_T (WAVES_PER_BLOCK * 64)
#define BLOCKS_PER_BATCH 192
#define GRID (BQ_B * BLOCKS_PER_BATCH)                        // 768
#define WAVES_PER_BATCH (BLOCKS_PER_BATCH * WAVES_PER_BLOCK)  // 1536

__global__ __launch_bounds__(BLOCK_T) void ballq_scan_kernel(
    const float* __restrict__ pc,    // (B, N, 3)
    const float* __restrict__ mask,  // (B, N, C)
    float* __restrict__ partial)     // (GRID,) unscaled per-block sums
{
    __shared__ __align__(16) float spc[BQ_N * 3];  // 48 KB: this batch's pc
    __shared__ float wsum[WAVES_PER_BLOCK];

    const int tid  = threadIdx.x;
    const int lane = tid & 63;
    const int wave = tid >> 6;
    const int b        = blockIdx.x / BLOCKS_PER_BATCH;
    const int blk_in_b = blockIdx.x % BLOCKS_PER_BATCH;

    const float* pcb   = pc   + (size_t)b * BQ_N * 3;
    const float* maskb = mask + (size_t)b * BQ_N * BQ_C;

    // Cooperative stage: 12288 floats = 3072 float4 / 512 threads = 6 each.
    {
        const float4* src = (const float4*)pcb;
        float4* dst = (float4*)spc;
        #pragma unroll
        for (int i = 0; i < (BQ_N * 3 / 4) / BLOCK_T; ++i)
            dst[tid + i * BLOCK_T] = src[tid + i * BLOCK_T];
    }
    __syncthreads();

    float acc = 0.f;  // per-lane sum across this wave's queries

    for (int n = blk_in_b * WAVES_PER_BLOCK + wave; n < BQ_N; n += WAVES_PER_BATCH) {
        const float qx = spc[n * 3 + 0];
        const float qy = spc[n * 3 + 1];
        const float qz = spc[n * 3 + 2];
        // Query row value for this lane's channel (one coalesced 2-line load).
        const float qv = (lane < BQ_C) ? maskb[(size_t)n * BQ_C + lane] : 0.f;

        // ---- Phase 1: peel first <=16 in-ball indices (no memory ops) ----
        int found  = 0;
        int first  = 0;   // self always in-ball => found >= 1
        int my_sel = 0;   // lane s (<16) holds slot s's neighbor index

        float cx = spc[lane * 3 + 0];
        float cy = spc[lane * 3 + 1];
        float cz = spc[lane * 3 + 2];

        for (int base = 0; base < BQ_N; base += 64) {
            // 1-deep LDS prefetch of the next chunk.
            const int nbase = (base + 64 < BQ_N) ? base + 64 : 0;
            const float nx = spc[(nbase + lane) * 3 + 0];
            const float ny = spc[(nbase + lane) * 3 + 1];
            const float nz = spc[(nbase + lane) * 3 + 2];

            const float dx = cx - qx, dy = cy - qy, dz = cz - qz;
            const float d2 = dx * dx + dy * dy + dz * dz;
            unsigned long long bal = __ballot(d2 < BQ_R2);

            while (bal && found < BQ_K) {        // wave-uniform, VALU-only
                const int bit = __builtin_ctzll(bal);
                bal &= bal - 1;
                const int msel = base + bit;
                if (found == 0) first = msel;
                if (lane == found) my_sel = msel;
                ++found;
            }
            if (found >= BQ_K) break;
            cx = nx; cy = ny; cz = nz;
        }
        // Pad remaining slots with first found index (reference semantics).
        if (lane < BQ_K && lane >= found) my_sel = first;

        // ---- Phase 2: batched gather — 16 independent coalesced loads ----
        float vals[BQ_K];
        #pragma unroll
        for (int s = 0; s < BQ_K; ++s) {
            const int nb = __shfl(my_sel, s, 64);  // v_readlane: SGPR base
            vals[s] = (lane < BQ_C) ? maskb[(size_t)nb * BQ_C + lane] : 0.f;
        }
        float lsum = 0.f;
        #pragma unroll
        for (int s = 0; s < BQ_K; ++s)
            lsum += fabsf(qv - vals[s]);

        acc += lsum;
    }

    // Wave reduction (64 lanes).
    for (int off = 32; off > 0; off >>= 1)
        acc += __shfl_xor(acc, off, 64);

    if (lane == 0) wsum[wave] = acc;
    __syncthreads();
    if (tid == 0) {
        float s = 0.f;
        #pragma unroll
        for (int w = 0; w < WAVES_PER_BLOCK; ++w) s += wsum[w];
        partial[blockIdx.x] = s;   // non-atomic per-block partial
    }
}

__global__ __launch_bounds__(256) void ballq_finish_kernel(
    const float* __restrict__ partial, float* __restrict__ out)
{
    float s = 0.f;
    for (int i = threadIdx.x; i < GRID; i += 256) s += partial[i];
    for (int off = 32; off > 0; off >>= 1)
        s += __shfl_xor(s, off, 64);
    __shared__ float ws[4];
    if ((threadIdx.x & 63) == 0) ws[threadIdx.x >> 6] = s;
    __syncthreads();
    if (threadIdx.x == 0)
        out[0] = (ws[0] + ws[1] + ws[2] + ws[3]) *
                 (1.0f / ((float)BQ_B * BQ_N * BQ_K));
}

extern "C" void kernel_launch(void* const* d_in, const int* in_sizes, int n_in,
                              void* d_out, int out_size, void* d_ws, size_t ws_size,
                              hipStream_t stream) {
    const float* pc   = (const float*)d_in[0];  // (4, 4096, 3)
    const float* mask = (const float*)d_in[1];  // (4, 4096, 30)
    float* out     = (float*)d_out;
    float* partial = (float*)d_ws;              // GRID floats = 3 KB scratch

    ballq_scan_kernel<<<GRID, BLOCK_T, 0, stream>>>(pc, mask, partial);
    ballq_finish_kernel<<<1, 256, 0, stream>>>(partial, out);
}